// Round 7
// baseline (200.801 us; speedup 1.0000x reference)
//
#include <hip/hip_runtime.h>
#include <math.h>

#define Bsz 2
#define Ssz 1024
#define Dsz 1024
#define Hn 16
#define DHsz 64
#define QKV3 3072
#define SCALE 0.125f

typedef __bf16 bf16;
typedef bf16 bf16x8 __attribute__((ext_vector_type(8)));
typedef bf16 bf16x4 __attribute__((ext_vector_type(4)));
typedef float f32x4 __attribute__((ext_vector_type(4)));

#define MFMA(a, b, c) __builtin_amdgcn_mfma_f32_16x16x32_bf16(a, b, c, 0, 0, 0)
#define LDT 72

// Interleaved score/prob layout: element index of (b, i, chunk, h, jc):
//   b*2^24 + i*16384 + chunk*4096 + h*256 + jc      (chunk = j>>8, jc = j&255)
// One (b,i,chunk) slab = [16 h][256 j] bf16 = 8 KB CONTIGUOUS — dape reads and
// rewrites exactly one slab per block (in-place, exclusive ownership).
#define SCSLAB(b, i, c) \
  ((size_t)(b) * 16777216 + (size_t)(i) * 16384 + (size_t)(c) * 4096)

// ---------------------------------------------------------------------------
// cast fp32 -> bf16 for all three operand tensors in ONE launch.
// ---------------------------------------------------------------------------
__global__ void cast_all(const float* __restrict__ x, const float* __restrict__ qw,
                         const float* __restrict__ ow, bf16* __restrict__ xh,
                         bf16* __restrict__ wh, bf16* __restrict__ owh) {
  int idx = (blockIdx.x * 256 + threadIdx.x) * 4;
  const float* src;
  bf16* dst;
  int off = idx;
  if (idx < 2097152) {
    src = x; dst = xh;
  } else if (idx < 2097152 + 3145728) {
    src = qw; dst = wh; off = idx - 2097152;
  } else {
    src = ow; dst = owh; off = idx - (2097152 + 3145728);
  }
  float4 v = *(const float4*)(src + off);
  bf16x4 hv = {(bf16)v.x, (bf16)v.y, (bf16)v.z, (bf16)v.w};
  *(bf16x4*)(dst + off) = hv;
}

// ---------------------------------------------------------------------------
// Fused tk table + wfrag.
// ---------------------------------------------------------------------------
__global__ void tk_wfrag(const float* __restrict__ bias_p, const float* __restrict__ bias_a,
                         const float* __restrict__ w1, const float* __restrict__ b1,
                         const float* __restrict__ w2, float2* __restrict__ tk,
                         bf16* __restrict__ wf) {
  if (blockIdx.x == 128) {
    int lane = threadIdx.x;
    if (lane < 64) {
      int l15 = lane & 15, q8 = (lane >> 4) << 3;
      bf16x8 w1d, w2a;
#pragma unroll
      for (int e = 0; e < 8; ++e) {
        int k = q8 + e;
        if (k < 16) {
          w1d[e] = (bf16)w1[l15 * 32 + k];
        } else {
          float w = w1[l15 * 32 + k - 16];
          w1d[e] = (bf16)(w - (float)(bf16)w);
        }
        w2a[e] = (bf16)w2[l15 * 16 + (k & 15)];
      }
      *(bf16x8*)(wf + lane * 8) = w1d;
      *(bf16x8*)(wf + 512 + lane * 8) = w2a;
    }
    return;
  }
  int idx = blockIdx.x * 256 + threadIdx.x;  // 32768
  int o = idx >> 4, n = idx & 15;
  int d = o - 1024; if (d < 0) d = -d; if (d > 1023) d = 1023;
  float fd = (float)d;
  float t1 = b1[n];
  float t2 = 0.f;
#pragma unroll
  for (int h = 0; h < 16; ++h) {
    float kb = -fmaxf(bias_p[h], 0.01f) * log1pf(fmaxf(bias_a[h], 0.01f) * fd);
    t1 += w1[n * 32 + 16 + h] * kb;
    if (h == n) t2 = kb;
  }
  tk[idx] = make_float2(t1, t2);
}

// ---------------------------------------------------------------------------
// K1: qkv_bf = bf16( x_h @ w_h^T )  tile 128x96 (round-4 verified).
// ---------------------------------------------------------------------------
__global__ __launch_bounds__(256, 3) void k1_qkv(const bf16* __restrict__ A,
                                                 const bf16* __restrict__ B,
                                                 bf16* __restrict__ C) {
  __shared__ __align__(16) bf16 sA[128 * LDT];
  __shared__ __align__(16) bf16 sB[96 * LDT];
  const int tid = threadIdx.x;
  const int lane = tid & 63, wv = tid >> 6;
  const int wr = wv >> 1, wc = wv & 1;
  const int l15 = lane & 15, q8 = (lane >> 4) << 3, q4 = (lane >> 4) << 2;
  const int m0 = blockIdx.y * 128, n0 = blockIdx.x * 96;
  const int r0 = tid >> 3, c8 = (tid & 7) << 3;

  f32x4 acc[4][3];
#pragma unroll
  for (int t = 0; t < 4; ++t)
#pragma unroll
    for (int u = 0; u < 3; ++u)
#pragma unroll
      for (int r = 0; r < 4; ++r) acc[t][u][r] = 0.f;

  bf16x8 rA[4], rB[3];
#define K1_LOAD(kt)                                                         \
  {                                                                         \
    _Pragma("unroll") for (int c = 0; c < 4; ++c)                           \
      rA[c] = *(const bf16x8*)(A + (size_t)(m0 + c * 32 + r0) * Dsz + (kt) + c8);  \
    _Pragma("unroll") for (int c = 0; c < 3; ++c)                           \
      rB[c] = *(const bf16x8*)(B + (size_t)(n0 + c * 32 + r0) * Dsz + (kt) + c8);  \
  }

  K1_LOAD(0)
  for (int kt = 0; kt < Dsz; kt += 64) {
    __syncthreads();
#pragma unroll
    for (int c = 0; c < 4; ++c) *(bf16x8*)&sA[(c * 32 + r0) * LDT + c8] = rA[c];
#pragma unroll
    for (int c = 0; c < 3; ++c) *(bf16x8*)&sB[(c * 32 + r0) * LDT + c8] = rB[c];
    __syncthreads();
    if (kt + 64 < Dsz) K1_LOAD(kt + 64)
#pragma unroll
    for (int ks = 0; ks < 64; ks += 32) {
      bf16x8 fa[4], fb[3];
#pragma unroll
      for (int t = 0; t < 4; ++t)
        fa[t] = *(const bf16x8*)&sA[(wr * 64 + t * 16 + l15) * LDT + ks + q8];
#pragma unroll
      for (int u = 0; u < 3; ++u)
        fb[u] = *(const bf16x8*)&sB[(wc * 48 + u * 16 + l15) * LDT + ks + q8];
#pragma unroll
      for (int t = 0; t < 4; ++t)
#pragma unroll
        for (int u = 0; u < 3; ++u) acc[t][u] = MFMA(fa[t], fb[u], acc[t][u]);
    }
  }
#undef K1_LOAD

#define K1BST 104
  bf16* sBounce = sA;
#pragma unroll
  for (int t = 0; t < 4; ++t) {
    __syncthreads();
#pragma unroll
    for (int u = 0; u < 3; ++u) {
      int col = wc * 48 + u * 16 + l15;
#pragma unroll
      for (int r = 0; r < 4; ++r)
        sBounce[(wr * 16 + q4 + r) * K1BST + col] = (bf16)acc[t][u][r];
    }
    __syncthreads();
    int lr = tid >> 3;                 // 0..31
    int grow = m0 + (lr < 16 ? t * 16 + lr : 64 + t * 16 + (lr - 16));
#pragma unroll
    for (int cg = 0; cg < 3; ++cg) {
      int cc = cg * 32 + (tid & 7) * 4;  // bf16x4 units over 96 cols
      bf16x4 vv = *(const bf16x4*)&sBounce[lr * K1BST + cc];
      *(bf16x4*)(C + (size_t)grow * QKV3 + n0 + cc) = vv;
    }
  }
#undef K1BST
}

// ---------------------------------------------------------------------------
// pack V transposed: v_t[b][h][d][j]
// ---------------------------------------------------------------------------
__global__ void pack_vt(const bf16* __restrict__ qkv, bf16* __restrict__ vt) {
  __shared__ __align__(16) bf16 T[64 * LDT];
  const int tid = threadIdx.x;
  const int bh = blockIdx.y, b = bh >> 4, h = bh & 15;
  const int j0 = blockIdx.x * 64;
#pragma unroll
  for (int c = 0; c < 2; ++c) {
    int lin = c * 256 + tid;
    int jr = lin >> 3, d8 = (lin & 7) << 3;
    bf16x8 v = *(const bf16x8*)(qkv + (size_t)(b * Ssz + j0 + jr) * QKV3 + 2048 + h * DHsz + d8);
#pragma unroll
    for (int e = 0; e < 8; ++e) T[(d8 + e) * LDT + jr] = v[e];
  }
  __syncthreads();
#pragma unroll
  for (int c = 0; c < 2; ++c) {
    int lin = c * 256 + tid;
    int d = lin >> 3, j8 = (lin & 7) << 3;
    bf16x8 o = *(const bf16x8*)&T[d * LDT + j8];
    *(bf16x8*)(vt + ((size_t)(b * Hn + h) * DHsz + d) * Ssz + j0 + j8) = o;
  }
}

// ---------------------------------------------------------------------------
// K2: scores = bf16( SCALE * Q @ K^T ) into the INTERLEAVED slab layout.
// Only the epilogue write address changed vs the round-4 verified kernel.
// ---------------------------------------------------------------------------
__global__ __launch_bounds__(256, 3) void k2_qk(const bf16* __restrict__ qkv,
                                                bf16* __restrict__ scores) {
  __shared__ __align__(16) bf16 sA[128 * LDT], sB[128 * LDT];
  const int tid = threadIdx.x;
  const int lane = tid & 63, wv = tid >> 6;
  const int wr = wv >> 1, wc = wv & 1;
  const int l15 = lane & 15, q8 = (lane >> 4) << 3, q4 = (lane >> 4) << 2;
  const int z = blockIdx.z, b = z >> 4, h = z & 15;
  const int i0 = blockIdx.y * 128, j0 = blockIdx.x * 128;
  const bf16* Ab = qkv + (size_t)b * Ssz * QKV3 + h * DHsz;
  const bf16* Bb = Ab + Ssz;
  const int r0 = tid >> 3, c8 = (tid & 7) << 3;
#pragma unroll
  for (int c = 0; c < 4; ++c) {
    int row = c * 32 + r0;
    *(bf16x8*)&sA[row * LDT + c8] = *(const bf16x8*)(Ab + (size_t)(i0 + row) * QKV3 + c8);
    *(bf16x8*)&sB[row * LDT + c8] = *(const bf16x8*)(Bb + (size_t)(j0 + row) * QKV3 + c8);
  }
  __syncthreads();
  f32x4 acc[4][4];
#pragma unroll
  for (int t = 0; t < 4; ++t)
#pragma unroll
    for (int u = 0; u < 4; ++u)
#pragma unroll
      for (int r = 0; r < 4; ++r) acc[t][u][r] = 0.f;
#pragma unroll
  for (int ks = 0; ks < 64; ks += 32) {
    bf16x8 fa[4], fb[4];
#pragma unroll
    for (int t = 0; t < 4; ++t) fa[t] = *(const bf16x8*)&sA[(wr * 64 + t * 16 + l15) * LDT + ks + q8];
#pragma unroll
    for (int u = 0; u < 4; ++u) fb[u] = *(const bf16x8*)&sB[(wc * 64 + u * 16 + l15) * LDT + ks + q8];
#pragma unroll
    for (int t = 0; t < 4; ++t)
#pragma unroll
      for (int u = 0; u < 4; ++u) acc[t][u] = MFMA(fa[t], fb[u], acc[t][u]);
  }

  // ---- epilogue: bounce 32x128 row-chunks through LDS, store bf16x8 to
  //      slab layout: chunk = j0>>8 (constant), jc = (j0&128) + cc ----
#define K2BST 136
  bf16* sBounce = sA;
  const int chnk = j0 >> 8, jhalf = j0 & 128;
  bf16* base2 = scores + SCSLAB(b, 0, chnk) + h * 256 + jhalf;
#pragma unroll
  for (int t = 0; t < 4; ++t) {
    __syncthreads();
#pragma unroll
    for (int u = 0; u < 4; ++u) {
      int col = wc * 64 + u * 16 + l15;
#pragma unroll
      for (int r = 0; r < 4; ++r)
        sBounce[(wr * 16 + q4 + r) * K2BST + col] = (bf16)(acc[t][u][r] * SCALE);
    }
    __syncthreads();
#pragma unroll
    for (int hf = 0; hf < 2; ++hf) {
      int lr = hf * 16 + (tid >> 4);       // 0..31
      int cc = (tid & 15) * 8;             // bf16x8 units over 128 cols
      bf16x8 vv = *(const bf16x8*)&sBounce[lr * K2BST + cc];
      int grow = i0 + (lr < 16 ? t * 16 + lr : 64 + t * 16 + (lr - 16));
      *(bf16x8*)(base2 + (size_t)grow * 16384 + cc) = vv;
    }
  }
#undef K2BST
}

// ---------------------------------------------------------------------------
// K3: DAPE MLP v9 — round-4 verified compute core (v7), slab-layout I/O:
// block (c,i,b) reads ONE contiguous 8 KB slab and rewrites it in place.
// ---------------------------------------------------------------------------
__device__ __forceinline__ float gelu_fast(float x) {
  float z = fabsf(x) * 0.70710678118654752f;
  float t = __builtin_amdgcn_rcpf(fmaf(0.47047f, z, 1.0f));
  float poly = t * fmaf(t, fmaf(t, 0.7478556f, -0.0958798f), 0.3480242f);
  float erfa = 1.0f - poly * __expf(-z * z);
  float erfs = copysignf(erfa, x);
  return 0.5f * x * (1.0f + erfs);
}

#define SHS 264  // sH row stride (bf16)

__global__ __launch_bounds__(256, 8) void dape_softmax(bf16* scores,
                                                       const float2* __restrict__ tk,
                                                       const bf16* __restrict__ wf,
                                                       const float* __restrict__ b2,
                                                       float* __restrict__ sums) {
  const int c = blockIdx.x;   // chunk 0..3 (256 j each)
  const int i = blockIdx.y;   // query row
  const int b = blockIdx.z;   // batch
  const int tid = threadIdx.x;
  const int lane = tid & 63, wv = tid >> 6;
  const int l15 = lane & 15, q = lane >> 4;
  const int q8 = q << 3, q4 = q << 2;

  __shared__ bf16 sH[Hn][SHS];                      // 8448 B raw bf16 scores
  __shared__ __align__(16) bf16 hdnS[4][2][16][40]; // 10240 B, dbuf by jt&1
  __shared__ float sumLDS[4][16];                   // 256 B

  const bf16x8 w1d = *(const bf16x8*)(wf + lane * 8);
  const bf16x8 w2a = *(const bf16x8*)(wf + 512 + lane * 8);
  const float bias2 = b2[l15];

  if (lane < 32) {
    int row = lane >> 1, col = 16 + (lane & 1) * 8;
    *(bf16x8*)&hdnS[wv][0][row][col] = (bf16x8){};
    *(bf16x8*)&hdnS[wv][1][row][col] = (bf16x8){};
  }

  // ---- stage this wave's 64-j slice of all 16 heads from the slab ----
  const int jw = wv * 64;
  bf16* slab = scores + SCSLAB(b, i, c);
#pragma unroll
  for (int t = 0; t < 2; ++t) {
    int h = t * 8 + (lane >> 3);
    int col = jw + (lane & 7) * 8;
    *(bf16x8*)&sH[h][col] = *(const bf16x8*)(slab + h * 256 + col);
  }
  // no barrier: each wave touches only its own j-columns.

  // tk pointer: o = (global j) - i + 1024, linear in j
  const float2* tkp = tk + ((size_t)(c * 256 + jw + q4 - i + 1024) << 4) + l15;
  bf16* prow = slab + l15 * 256 + jw;  // head l15, this wave's j window
  float psum = 0.f;

#pragma unroll
  for (int jt = 0; jt < 4; ++jt) {
    const int j0c = jw + jt * 16;
    bf16x8 a1;
#pragma unroll
    for (int e = 0; e < 8; ++e) a1[e] = sH[(q8 + e) & 15][j0c + l15];
    float2 tkv[4];
#pragma unroll
    for (int r = 0; r < 4; ++r) tkv[r] = tkp[jt * 256 + r * 16];
    f32x4 c1 = {tkv[0].x, tkv[1].x, tkv[2].x, tkv[3].x};
    c1 = MFMA(a1, w1d, c1);
#pragma unroll
    for (int r = 0; r < 4; ++r) hdnS[wv][jt & 1][q4 + r][l15] = (bf16)gelu_fast(c1[r]);
    bf16x8 a2 = *(const bf16x8*)&hdnS[wv][jt & 1][l15][q8];
    f32x4 c2 = {bias2, bias2, bias2, bias2};
    c2 = MFMA(a2, w2a, c2);
    bf16x4 sc4 = *(const bf16x4*)&sH[l15][j0c + q4];
    f32x4 pv;
#pragma unroll
    for (int r = 0; r < 4; ++r) {
      float lg = (float)sc4[r] + tkv[r].y + c2[r];
      pv[r] = __expf(lg);          // no max-sub; logits bounded
      psum += pv[r];
    }
    bf16x4 p4 = {(bf16)pv[0], (bf16)pv[1], (bf16)pv[2], (bf16)pv[3]};
    *(bf16x4*)(prow + jt * 16 + q4) = p4;
  }

  // ---- chunk sum: reduce the 4 q-lanes, then across the 4 waves via LDS ----
  psum += __shfl_xor(psum, 16, 64);
  psum += __shfl_xor(psum, 32, 64);
  if (lane < 16) sumLDS[wv][lane] = psum;
  __syncthreads();
  if (tid < 16) {
    float tot = sumLDS[0][tid] + sumLDS[1][tid] + sumLDS[2][tid] + sumLDS[3][tid];
    sums[((((b << 10) + i) << 4) + tid) * 4 + c] = tot;
  }
}

// ---------------------------------------------------------------------------
// K4: aout = (P_un @ V) / sum(chunks); A-operand read from slab layout.
// ---------------------------------------------------------------------------
__global__ __launch_bounds__(256, 6) void k4_av(const bf16* __restrict__ attn,
                                                const bf16* __restrict__ vt,
                                                const float* __restrict__ sums,
                                                bf16* __restrict__ aout) {
  __shared__ __align__(16) bf16 sA[64 * LDT], sB[64 * LDT];
  const int tid = threadIdx.x;
  const int lane = tid & 63, wv = tid >> 6;
  const int wr = wv >> 1, wc = wv & 1;
  const int l15 = lane & 15, q8 = (lane >> 4) << 3, q4 = (lane >> 4) << 2;
  const int i0 = blockIdx.x * 64, h = blockIdx.y, b = blockIdx.z;
  // A(row, kt+jc) = attn[SCSLAB(b, i0+row, kt>>8) + h*256 + (kt&255) + jc]
  const bf16* Ab = attn + SCSLAB(b, i0, 0) + h * 256;
  const bf16* Bb = vt + (size_t)(b * Hn + h) * DHsz * Ssz;
  const int r0 = tid >> 3, c8 = (tid & 7) << 3;
  f32x4 acc[2][2];
#pragma unroll
  for (int t = 0; t < 2; ++t)
#pragma unroll
    for (int u = 0; u < 2; ++u)
#pragma unroll
      for (int r = 0; r < 4; ++r) acc[t][u][r] = 0.f;
  bf16x8 rA[2], rB[2];
#define K4_LOAD(kt)                                                          \
  {                                                                          \
    _Pragma("unroll") for (int c = 0; c < 2; ++c) {                          \
      int row = c * 32 + r0;                                                 \
      rA[c] = *(const bf16x8*)(Ab + (size_t)row * 16384 +                    \
                               (((kt) >> 8) * 4096) + ((kt) & 255) + c8);    \
      rB[c] = *(const bf16x8*)(Bb + ((size_t)row << 10) + (kt) + c8);        \
    }                                                                        \
  }
  K4_LOAD(0)
  for (int kt = 0; kt < Ssz; kt += 64) {
    __syncthreads();
#pragma unroll
    for (int c = 0; c < 2; ++c) {
      int row = c * 32 + r0;
      *(bf16x8*)&sA[row * LDT + c8] = rA[c];
      *(bf16x8*)&sB[row * LDT + c8] = rB[c];
    }
    __syncthreads();
    if (kt + 64 < Ssz) K4_LOAD(kt + 64)
#pragma unroll
    for (int ks = 0; ks < 64; ks += 32) {
      bf16x8 fa[2], fb[2];
#pragma unroll
      for (int t = 0; t < 2; ++t) fa[t] = *(const bf16x8*)&sA[(wr * 32 + t * 16 + l15) * LDT + ks + q8];
#pragma unroll
      for (int u = 0; u < 2; ++u) fb[u] = *(const bf16x8*)&sB[(wc * 32 + u * 16 + l15) * LDT + ks + q8];
#pragma unroll
      for (int t = 0; t < 2; ++t)
#pragma unroll
        for (int u = 0; u < 2; ++u) acc[t][u] = MFMA(fa[t], fb[u], acc[t][u]);
    }
  }
#undef K4_LOAD

  // ---- epilogue: divide, bounce full 64x64 tile through LDS, store bf16x8 ----
  bf16* sBounce = sA;
  __syncthreads();
#pragma unroll
  for (int t = 0; t < 2; ++t)
#pragma unroll
    for (int r = 0; r < 4; ++r) {
      int lr = wr * 32 + t * 16 + q4 + r;
      int row = i0 + lr;
      f32x4 sv = *(const f32x4*)&sums[((((b << 10) + row) << 4) + h) * 4];
      float inv = 1.f / (sv[0] + sv[1] + sv[2] + sv[3]);
#pragma unroll
      for (int u = 0; u < 2; ++u)
        sBounce[lr * LDT + wc * 32 + u * 16 + l15] = (bf16)(acc[t][u][r] * inv);
    }
  __syncthreads();
#pragma unroll
  for (int r2 = 0; r2 < 2; ++r2) {
    int lr = r2 * 32 + (tid >> 3);       // 0..63
    int cc = (tid & 7) * 8;              // bf16x8 units over 64 cols
    bf16x8 vv = *(const bf16x8*)&sBounce[lr * LDT + cc];
    *(bf16x8*)(aout + (size_t)(b * Ssz + i0 + lr) * Dsz + h * DHsz + cc) = vv;
  }
}

// ---------------------------------------------------------------------------
// K5: out = aout_bf @ ow_h^T  1-term, fp32 out, tile 64x64 (round-4 verified).
// ---------------------------------------------------------------------------
__global__ __launch_bounds__(256, 6) void k5_out(const bf16* __restrict__ A,
                                                 const bf16* __restrict__ B,
                                                 float* __restrict__ C) {
  __shared__ __align__(16) bf16 sA[64 * LDT], sB[64 * LDT];
  const int tid = threadIdx.x;
  const int lane = tid & 63, wv = tid >> 6;
  const int wr = wv >> 1, wc = wv & 1;
  const int l15 = lane & 15, q8 = (lane >> 4) << 3, q4 = (lane >> 4) << 2;
  const int m0 = blockIdx.y * 64, n0 = blockIdx.x * 64;
  const int r0 = tid >> 3, c8 = (tid & 7) << 3;
  f32x4 acc[2][2];
#pragma unroll
  for (int t = 0; t < 2; ++t)
#pragma unroll
    for (int u = 0; u < 2; ++u)
#pragma unroll
      for (int r = 0; r < 4; ++r) acc[t][u][r] = 0.f;
  bf16x8 rA[2], rB[2];
#define K5_LOAD(kt)                                                       \
  {                                                                       \
    _Pragma("unroll") for (int c = 0; c < 2; ++c) {                       \
      int row = c * 32 + r0;                                              \
      rA[c] = *(const bf16x8*)(A + (size_t)(m0 + row) * Dsz + (kt) + c8);   \
      rB[c] = *(const bf16x8*)(B + (size_t)(n0 + row) * Dsz + (kt) + c8);   \
    }                                                                     \
  }
  K5_LOAD(0)
  for (int kt = 0; kt < Dsz; kt += 64) {
    __syncthreads();
#pragma unroll
    for (int c = 0; c < 2; ++c) {
      int row = c * 32 + r0;
      *(bf16x8*)&sA[row * LDT + c8] = rA[c];
      *(bf16x8*)&sB[row * LDT + c8] = rB[c];
    }
    __syncthreads();
    if (kt + 64 < Dsz) K5_LOAD(kt + 64)
#pragma unroll
    for (int ks = 0; ks < 64; ks += 32) {
      bf16x8 fa[2], fb[2];
#pragma unroll
      for (int t = 0; t < 2; ++t) fa[t] = *(const bf16x8*)&sA[(wr * 32 + t * 16 + l15) * LDT + ks + q8];
#pragma unroll
      for (int u = 0; u < 2; ++u) fb[u] = *(const bf16x8*)&sB[(wc * 32 + u * 16 + l15) * LDT + ks + q8];
#pragma unroll
      for (int t = 0; t < 2; ++t)
#pragma unroll
        for (int u = 0; u < 2; ++u) acc[t][u] = MFMA(fa[t], fb[u], acc[t][u]);
    }
  }
#pragma unroll
  for (int t = 0; t < 2; ++t)
#pragma unroll
    for (int u = 0; u < 2; ++u) {
      int col = n0 + wc * 32 + u * 16 + l15;
#pragma unroll
      for (int r = 0; r < 4; ++r) {
        int row = m0 + wr * 32 + t * 16 + q4 + r;
        C[(size_t)row * Dsz + col] = acc[t][u][r];
      }
    }
#undef K5_LOAD
}

// ---------------------------------------------------------------------------
extern "C" void kernel_launch(void* const* d_in, const int* in_sizes, int n_in,
                              void* d_out, int out_size, void* d_ws, size_t ws_size,
                              hipStream_t stream) {
  const float* x      = (const float*)d_in[0];
  const float* qkv_w  = (const float*)d_in[1];
  const float* out_w  = (const float*)d_in[2];
  const float* bias_p = (const float*)d_in[3];
  const float* bias_a = (const float*)d_in[4];
  const float* w1     = (const float*)d_in[5];
  const float* b1     = (const float*)d_in[6];
  const float* w2     = (const float*)d_in[7];
  const float* b2     = (const float*)d_in[8];
  float* out = (float*)d_out;

  // ws layout (bytes). scores (64 MB) ALIASES x_h/w_h (dead after k1).
  char* ws = (char*)d_ws;
  const size_t MB = 1ull << 20;
  bf16* ow_h   = (bf16*)(ws + 0 * MB);            // 2 MB
  bf16* qkv_bf = (bf16*)(ws + 2 * MB);            // 12 MB
  bf16* v_t    = (bf16*)(ws + 14 * MB);           // 4 MB
  bf16* aout   = (bf16*)(ws + 18 * MB);           // 4 MB
  float* sums  = (float*)(ws + 22 * MB + 65536);  // 512 KB [b][i][h][chunk]
  bf16* wf     = (bf16*)(ws + 22 * MB + 589824);  // 2 KB
  float2* tk   = (float2*)(ws + 22 * MB + 655360);// 256 KB [o][n]
  bf16* x_h    = (bf16*)(ws + 23 * MB);           // 4 MB   (dead after k1)
  bf16* w_h    = (bf16*)(ws + 27 * MB);           // 6 MB   (dead after k1)
  bf16* sc_bf  = (bf16*)(ws + 23 * MB);           // 64 MB, ends at 87 MB

  cast_all<<<6144, 256, 0, stream>>>(x, qkv_w, out_w, x_h, w_h, ow_h);
  tk_wfrag<<<129, 256, 0, stream>>>(bias_p, bias_a, w1, b1, w2, tk, wf);

  k1_qkv<<<dim3(QKV3 / 96, (Bsz * Ssz) / 128), 256, 0, stream>>>(x_h, w_h, qkv_bf);
  pack_vt<<<dim3(Ssz / 64, Bsz * Hn), 256, 0, stream>>>(qkv_bf, v_t);

  k2_qk<<<dim3(Ssz / 128, Ssz / 128, Bsz * Hn), 256, 0, stream>>>(qkv_bf, sc_bf);
  dape_softmax<<<dim3(4, Ssz, Bsz), 256, 0, stream>>>(sc_bf, tk, wf, b2, sums);
  k4_av<<<dim3(Ssz / 64, Hn, Bsz), 256, 0, stream>>>(sc_bf, v_t, sums, aout);

  k5_out<<<dim3(Dsz / 64, (Bsz * Ssz) / 64), 256, 0, stream>>>(aout, ow_h, out);
}

// Round 8
// 197.564 us; speedup vs baseline: 1.0164x; 1.0164x over previous
//
#include <hip/hip_runtime.h>
#include <math.h>

#define Bsz 2
#define Ssz 1024
#define Dsz 1024
#define Hn 16
#define DHsz 64
#define QKV3 3072
#define SCALE 0.125f

typedef __bf16 bf16;
typedef bf16 bf16x8 __attribute__((ext_vector_type(8)));
typedef bf16 bf16x4 __attribute__((ext_vector_type(4)));
typedef float f32x4 __attribute__((ext_vector_type(4)));

#define MFMA(a, b, c) __builtin_amdgcn_mfma_f32_16x16x32_bf16(a, b, c, 0, 0, 0)
#define LDT 72

// Interleaved score/prob layout: element index of (b, i, chunk, h, jc):
//   b*2^24 + i*16384 + chunk*4096 + h*256 + jc      (chunk = j>>8, jc = j&255)
// One (b,i) group = 4 chunks = 32 KB contiguous; dape block owns all of it.
#define SCSLAB(b, i, c) \
  ((size_t)(b) * 16777216 + (size_t)(i) * 16384 + (size_t)(c) * 4096)

// ---------------------------------------------------------------------------
// cast fp32 -> bf16 for all three operand tensors in ONE launch.
// ---------------------------------------------------------------------------
__global__ void cast_all(const float* __restrict__ x, const float* __restrict__ qw,
                         const float* __restrict__ ow, bf16* __restrict__ xh,
                         bf16* __restrict__ wh, bf16* __restrict__ owh) {
  int idx = (blockIdx.x * 256 + threadIdx.x) * 4;
  const float* src;
  bf16* dst;
  int off = idx;
  if (idx < 2097152) {
    src = x; dst = xh;
  } else if (idx < 2097152 + 3145728) {
    src = qw; dst = wh; off = idx - 2097152;
  } else {
    src = ow; dst = owh; off = idx - (2097152 + 3145728);
  }
  float4 v = *(const float4*)(src + off);
  bf16x4 hv = {(bf16)v.x, (bf16)v.y, (bf16)v.z, (bf16)v.w};
  *(bf16x4*)(dst + off) = hv;
}

// ---------------------------------------------------------------------------
// Fused tk table + wfrag.
// ---------------------------------------------------------------------------
__global__ void tk_wfrag(const float* __restrict__ bias_p, const float* __restrict__ bias_a,
                         const float* __restrict__ w1, const float* __restrict__ b1,
                         const float* __restrict__ w2, float2* __restrict__ tk,
                         bf16* __restrict__ wf) {
  if (blockIdx.x == 128) {
    int lane = threadIdx.x;
    if (lane < 64) {
      int l15 = lane & 15, q8 = (lane >> 4) << 3;
      bf16x8 w1d, w2a;
#pragma unroll
      for (int e = 0; e < 8; ++e) {
        int k = q8 + e;
        if (k < 16) {
          w1d[e] = (bf16)w1[l15 * 32 + k];
        } else {
          float w = w1[l15 * 32 + k - 16];
          w1d[e] = (bf16)(w - (float)(bf16)w);
        }
        w2a[e] = (bf16)w2[l15 * 16 + (k & 15)];
      }
      *(bf16x8*)(wf + lane * 8) = w1d;
      *(bf16x8*)(wf + 512 + lane * 8) = w2a;
    }
    return;
  }
  int idx = blockIdx.x * 256 + threadIdx.x;  // 32768
  int o = idx >> 4, n = idx & 15;
  int d = o - 1024; if (d < 0) d = -d; if (d > 1023) d = 1023;
  float fd = (float)d;
  float t1 = b1[n];
  float t2 = 0.f;
#pragma unroll
  for (int h = 0; h < 16; ++h) {
    float kb = -fmaxf(bias_p[h], 0.01f) * log1pf(fmaxf(bias_a[h], 0.01f) * fd);
    t1 += w1[n * 32 + 16 + h] * kb;
    if (h == n) t2 = kb;
  }
  tk[idx] = make_float2(t1, t2);
}

// ---------------------------------------------------------------------------
// K1: qkv_bf = bf16( x_h @ w_h^T )  tile 128x96 (round-4 verified).
// ---------------------------------------------------------------------------
__global__ __launch_bounds__(256, 3) void k1_qkv(const bf16* __restrict__ A,
                                                 const bf16* __restrict__ B,
                                                 bf16* __restrict__ C) {
  __shared__ __align__(16) bf16 sA[128 * LDT];
  __shared__ __align__(16) bf16 sB[96 * LDT];
  const int tid = threadIdx.x;
  const int lane = tid & 63, wv = tid >> 6;
  const int wr = wv >> 1, wc = wv & 1;
  const int l15 = lane & 15, q8 = (lane >> 4) << 3, q4 = (lane >> 4) << 2;
  const int m0 = blockIdx.y * 128, n0 = blockIdx.x * 96;
  const int r0 = tid >> 3, c8 = (tid & 7) << 3;

  f32x4 acc[4][3];
#pragma unroll
  for (int t = 0; t < 4; ++t)
#pragma unroll
    for (int u = 0; u < 3; ++u)
#pragma unroll
      for (int r = 0; r < 4; ++r) acc[t][u][r] = 0.f;

  bf16x8 rA[4], rB[3];
#define K1_LOAD(kt)                                                         \
  {                                                                         \
    _Pragma("unroll") for (int c = 0; c < 4; ++c)                           \
      rA[c] = *(const bf16x8*)(A + (size_t)(m0 + c * 32 + r0) * Dsz + (kt) + c8);  \
    _Pragma("unroll") for (int c = 0; c < 3; ++c)                           \
      rB[c] = *(const bf16x8*)(B + (size_t)(n0 + c * 32 + r0) * Dsz + (kt) + c8);  \
  }

  K1_LOAD(0)
  for (int kt = 0; kt < Dsz; kt += 64) {
    __syncthreads();
#pragma unroll
    for (int c = 0; c < 4; ++c) *(bf16x8*)&sA[(c * 32 + r0) * LDT + c8] = rA[c];
#pragma unroll
    for (int c = 0; c < 3; ++c) *(bf16x8*)&sB[(c * 32 + r0) * LDT + c8] = rB[c];
    __syncthreads();
    if (kt + 64 < Dsz) K1_LOAD(kt + 64)
#pragma unroll
    for (int ks = 0; ks < 64; ks += 32) {
      bf16x8 fa[4], fb[3];
#pragma unroll
      for (int t = 0; t < 4; ++t)
        fa[t] = *(const bf16x8*)&sA[(wr * 64 + t * 16 + l15) * LDT + ks + q8];
#pragma unroll
      for (int u = 0; u < 3; ++u)
        fb[u] = *(const bf16x8*)&sB[(wc * 48 + u * 16 + l15) * LDT + ks + q8];
#pragma unroll
      for (int t = 0; t < 4; ++t)
#pragma unroll
        for (int u = 0; u < 3; ++u) acc[t][u] = MFMA(fa[t], fb[u], acc[t][u]);
    }
  }
#undef K1_LOAD

#define K1BST 104
  bf16* sBounce = sA;
#pragma unroll
  for (int t = 0; t < 4; ++t) {
    __syncthreads();
#pragma unroll
    for (int u = 0; u < 3; ++u) {
      int col = wc * 48 + u * 16 + l15;
#pragma unroll
      for (int r = 0; r < 4; ++r)
        sBounce[(wr * 16 + q4 + r) * K1BST + col] = (bf16)acc[t][u][r];
    }
    __syncthreads();
    int lr = tid >> 3;                 // 0..31
    int grow = m0 + (lr < 16 ? t * 16 + lr : 64 + t * 16 + (lr - 16));
#pragma unroll
    for (int cg = 0; cg < 3; ++cg) {
      int cc = cg * 32 + (tid & 7) * 4;  // bf16x4 units over 96 cols
      bf16x4 vv = *(const bf16x4*)&sBounce[lr * K1BST + cc];
      *(bf16x4*)(C + (size_t)grow * QKV3 + n0 + cc) = vv;
    }
  }
#undef K1BST
}

// ---------------------------------------------------------------------------
// pack V transposed: v_t[b][h][d][j]
// ---------------------------------------------------------------------------
__global__ void pack_vt(const bf16* __restrict__ qkv, bf16* __restrict__ vt) {
  __shared__ __align__(16) bf16 T[64 * LDT];
  const int tid = threadIdx.x;
  const int bh = blockIdx.y, b = bh >> 4, h = bh & 15;
  const int j0 = blockIdx.x * 64;
#pragma unroll
  for (int c = 0; c < 2; ++c) {
    int lin = c * 256 + tid;
    int jr = lin >> 3, d8 = (lin & 7) << 3;
    bf16x8 v = *(const bf16x8*)(qkv + (size_t)(b * Ssz + j0 + jr) * QKV3 + 2048 + h * DHsz + d8);
#pragma unroll
    for (int e = 0; e < 8; ++e) T[(d8 + e) * LDT + jr] = v[e];
  }
  __syncthreads();
#pragma unroll
  for (int c = 0; c < 2; ++c) {
    int lin = c * 256 + tid;
    int d = lin >> 3, j8 = (lin & 7) << 3;
    bf16x8 o = *(const bf16x8*)&T[d * LDT + j8];
    *(bf16x8*)(vt + ((size_t)(b * Hn + h) * DHsz + d) * Ssz + j0 + j8) = o;
  }
}

// ---------------------------------------------------------------------------
// K2: scores = bf16( SCALE * Q @ K^T ) into the slab layout (round-7 verified).
// ---------------------------------------------------------------------------
__global__ __launch_bounds__(256, 3) void k2_qk(const bf16* __restrict__ qkv,
                                                bf16* __restrict__ scores) {
  __shared__ __align__(16) bf16 sA[128 * LDT], sB[128 * LDT];
  const int tid = threadIdx.x;
  const int lane = tid & 63, wv = tid >> 6;
  const int wr = wv >> 1, wc = wv & 1;
  const int l15 = lane & 15, q8 = (lane >> 4) << 3, q4 = (lane >> 4) << 2;
  const int z = blockIdx.z, b = z >> 4, h = z & 15;
  const int i0 = blockIdx.y * 128, j0 = blockIdx.x * 128;
  const bf16* Ab = qkv + (size_t)b * Ssz * QKV3 + h * DHsz;
  const bf16* Bb = Ab + Ssz;
  const int r0 = tid >> 3, c8 = (tid & 7) << 3;
#pragma unroll
  for (int c = 0; c < 4; ++c) {
    int row = c * 32 + r0;
    *(bf16x8*)&sA[row * LDT + c8] = *(const bf16x8*)(Ab + (size_t)(i0 + row) * QKV3 + c8);
    *(bf16x8*)&sB[row * LDT + c8] = *(const bf16x8*)(Bb + (size_t)(j0 + row) * QKV3 + c8);
  }
  __syncthreads();
  f32x4 acc[4][4];
#pragma unroll
  for (int t = 0; t < 4; ++t)
#pragma unroll
    for (int u = 0; u < 4; ++u)
#pragma unroll
      for (int r = 0; r < 4; ++r) acc[t][u][r] = 0.f;
#pragma unroll
  for (int ks = 0; ks < 64; ks += 32) {
    bf16x8 fa[4], fb[4];
#pragma unroll
    for (int t = 0; t < 4; ++t) fa[t] = *(const bf16x8*)&sA[(wr * 64 + t * 16 + l15) * LDT + ks + q8];
#pragma unroll
    for (int u = 0; u < 4; ++u) fb[u] = *(const bf16x8*)&sB[(wc * 64 + u * 16 + l15) * LDT + ks + q8];
#pragma unroll
    for (int t = 0; t < 4; ++t)
#pragma unroll
      for (int u = 0; u < 4; ++u) acc[t][u] = MFMA(fa[t], fb[u], acc[t][u]);
  }

#define K2BST 136
  bf16* sBounce = sA;
  const int chnk = j0 >> 8, jhalf = j0 & 128;
  bf16* base2 = scores + SCSLAB(b, 0, chnk) + h * 256 + jhalf;
#pragma unroll
  for (int t = 0; t < 4; ++t) {
    __syncthreads();
#pragma unroll
    for (int u = 0; u < 4; ++u) {
      int col = wc * 64 + u * 16 + l15;
#pragma unroll
      for (int r = 0; r < 4; ++r)
        sBounce[(wr * 16 + q4 + r) * K2BST + col] = (bf16)(acc[t][u][r] * SCALE);
    }
    __syncthreads();
#pragma unroll
    for (int hf = 0; hf < 2; ++hf) {
      int lr = hf * 16 + (tid >> 4);       // 0..31
      int cc = (tid & 15) * 8;             // bf16x8 units over 128 cols
      bf16x8 vv = *(const bf16x8*)&sBounce[lr * K2BST + cc];
      int grow = i0 + (lr < 16 ? t * 16 + lr : 64 + t * 16 + (lr - 16));
      *(bf16x8*)(base2 + (size_t)grow * 16384 + cc) = vv;
    }
  }
#undef K2BST
}

// ---------------------------------------------------------------------------
// K3: DAPE MLP v10 — one 1024-thread block per (i,b) owns all 4 chunks.
// Per-block staging-head/store-tail latency amortized 4x; 55.3 KB LDS ->
// 2 blocks/CU = 32 waves (100%). Wave w: chunk = w>>2, j-window = (w&3)*64.
// hdnS single-buffered per wave (dbuf was proven null); same-wave LDS ops
// are in-order so no sync needed across jt. Chunk sums reduced in-block with
// the EXACT same FP association as k4's old ((c0+c1)+c2)+c3 of ((w0+w1)+w2)+w3
// -> sums becomes one float per (b,i,h); k4 does a single load.
// ---------------------------------------------------------------------------
__device__ __forceinline__ float gelu_fast(float x) {
  float z = fabsf(x) * 0.70710678118654752f;
  float t = __builtin_amdgcn_rcpf(fmaf(0.47047f, z, 1.0f));
  float poly = t * fmaf(t, fmaf(t, 0.7478556f, -0.0958798f), 0.3480242f);
  float erfa = 1.0f - poly * __expf(-z * z);
  float erfs = copysignf(erfa, x);
  return 0.5f * x * (1.0f + erfs);
}

#define SHS 264  // sH row stride (bf16)

__global__ __launch_bounds__(1024, 8) void dape_softmax(bf16* scores,
                                                        const float2* __restrict__ tk,
                                                        const bf16* __restrict__ wf,
                                                        const float* __restrict__ b2,
                                                        float* __restrict__ sums) {
  const int i = blockIdx.x;   // query row
  const int b = blockIdx.y;   // batch
  const int tid = threadIdx.x;
  const int w = tid >> 6, lane = tid & 63;
  const int c = w >> 2;       // chunk 0..3
  const int l15 = lane & 15, q = lane >> 4;
  const int q8 = q << 3, q4 = q << 2;

  __shared__ bf16 sH[4][Hn][SHS];                 // 33.8 KB raw bf16 scores
  __shared__ __align__(16) bf16 hdnS[16][16][40]; // 20.5 KB, per wave
  __shared__ float sumLDS[16][16];                // 1 KB

  const bf16x8 w1d = *(const bf16x8*)(wf + lane * 8);
  const bf16x8 w2a = *(const bf16x8*)(wf + 512 + lane * 8);
  const float bias2 = b2[l15];

  if (lane < 32) {
    int row = lane >> 1, col = 16 + (lane & 1) * 8;
    *(bf16x8*)&hdnS[w][row][col] = (bf16x8){};
  }

  // ---- stage this wave's 64-j slice of all 16 heads from its chunk slab ----
  const int jw = (w & 3) * 64;
  bf16* slab = scores + SCSLAB(b, i, c);
#pragma unroll
  for (int t = 0; t < 2; ++t) {
    int h = t * 8 + (lane >> 3);
    int col = jw + (lane & 7) * 8;
    *(bf16x8*)&sH[c][h][col] = *(const bf16x8*)(slab + h * 256 + col);
  }
  // no barrier: each wave touches only its own (chunk, j-window) columns.

  // tk pointer: o = (global j) - i + 1024, linear in j
  const float2* tkp = tk + ((size_t)(c * 256 + jw + q4 - i + 1024) << 4) + l15;
  bf16* prow = slab + l15 * 256 + jw;  // head l15, this wave's j window
  float psum = 0.f;

#pragma unroll
  for (int jt = 0; jt < 4; ++jt) {
    const int j0c = jw + jt * 16;
    bf16x8 a1;
#pragma unroll
    for (int e = 0; e < 8; ++e) a1[e] = sH[c][(q8 + e) & 15][j0c + l15];
    float2 tkv[4];
#pragma unroll
    for (int r = 0; r < 4; ++r) tkv[r] = tkp[jt * 256 + r * 16];
    f32x4 c1 = {tkv[0].x, tkv[1].x, tkv[2].x, tkv[3].x};
    c1 = MFMA(a1, w1d, c1);
#pragma unroll
    for (int r = 0; r < 4; ++r) hdnS[w][q4 + r][l15] = (bf16)gelu_fast(c1[r]);
    bf16x8 a2 = *(const bf16x8*)&hdnS[w][l15][q8];
    f32x4 c2 = {bias2, bias2, bias2, bias2};
    c2 = MFMA(a2, w2a, c2);
    bf16x4 sc4 = *(const bf16x4*)&sH[c][l15][j0c + q4];
    f32x4 pv;
#pragma unroll
    for (int r = 0; r < 4; ++r) {
      float lg = (float)sc4[r] + tkv[r].y + c2[r];
      pv[r] = __expf(lg);          // no max-sub; logits bounded
      psum += pv[r];
    }
    bf16x4 p4 = {(bf16)pv[0], (bf16)pv[1], (bf16)pv[2], (bf16)pv[3]};
    *(bf16x4*)(prow + jt * 16 + q4) = p4;
  }

  // ---- row sum: q-lane reduce, then all 16 waves via LDS (order-preserving) ----
  psum += __shfl_xor(psum, 16, 64);
  psum += __shfl_xor(psum, 32, 64);
  if (lane < 16) sumLDS[w][lane] = psum;
  __syncthreads();
  if (tid < 16) {
    int h = tid;
    float s0 = ((sumLDS[0][h] + sumLDS[1][h]) + sumLDS[2][h]) + sumLDS[3][h];
    float s1 = ((sumLDS[4][h] + sumLDS[5][h]) + sumLDS[6][h]) + sumLDS[7][h];
    float s2 = ((sumLDS[8][h] + sumLDS[9][h]) + sumLDS[10][h]) + sumLDS[11][h];
    float s3 = ((sumLDS[12][h] + sumLDS[13][h]) + sumLDS[14][h]) + sumLDS[15][h];
    sums[(((b << 10) + i) << 4) + h] = ((s0 + s1) + s2) + s3;
  }
}

// ---------------------------------------------------------------------------
// K4: aout = (P_un @ V) / sum; slab-layout A reads; scalar sum load.
// ---------------------------------------------------------------------------
__global__ __launch_bounds__(256, 6) void k4_av(const bf16* __restrict__ attn,
                                                const bf16* __restrict__ vt,
                                                const float* __restrict__ sums,
                                                bf16* __restrict__ aout) {
  __shared__ __align__(16) bf16 sA[64 * LDT], sB[64 * LDT];
  const int tid = threadIdx.x;
  const int lane = tid & 63, wv = tid >> 6;
  const int wr = wv >> 1, wc = wv & 1;
  const int l15 = lane & 15, q8 = (lane >> 4) << 3, q4 = (lane >> 4) << 2;
  const int i0 = blockIdx.x * 64, h = blockIdx.y, b = blockIdx.z;
  const bf16* Ab = attn + SCSLAB(b, i0, 0) + h * 256;
  const bf16* Bb = vt + (size_t)(b * Hn + h) * DHsz * Ssz;
  const int r0 = tid >> 3, c8 = (tid & 7) << 3;
  f32x4 acc[2][2];
#pragma unroll
  for (int t = 0; t < 2; ++t)
#pragma unroll
    for (int u = 0; u < 2; ++u)
#pragma unroll
      for (int r = 0; r < 4; ++r) acc[t][u][r] = 0.f;
  bf16x8 rA[2], rB[2];
#define K4_LOAD(kt)                                                          \
  {                                                                          \
    _Pragma("unroll") for (int c = 0; c < 2; ++c) {                          \
      int row = c * 32 + r0;                                                 \
      rA[c] = *(const bf16x8*)(Ab + (size_t)row * 16384 +                    \
                               (((kt) >> 8) * 4096) + ((kt) & 255) + c8);    \
      rB[c] = *(const bf16x8*)(Bb + ((size_t)row << 10) + (kt) + c8);        \
    }                                                                        \
  }
  K4_LOAD(0)
  for (int kt = 0; kt < Ssz; kt += 64) {
    __syncthreads();
#pragma unroll
    for (int c = 0; c < 2; ++c) {
      int row = c * 32 + r0;
      *(bf16x8*)&sA[row * LDT + c8] = rA[c];
      *(bf16x8*)&sB[row * LDT + c8] = rB[c];
    }
    __syncthreads();
    if (kt + 64 < Ssz) K4_LOAD(kt + 64)
#pragma unroll
    for (int ks = 0; ks < 64; ks += 32) {
      bf16x8 fa[2], fb[2];
#pragma unroll
      for (int t = 0; t < 2; ++t) fa[t] = *(const bf16x8*)&sA[(wr * 32 + t * 16 + l15) * LDT + ks + q8];
#pragma unroll
      for (int u = 0; u < 2; ++u) fb[u] = *(const bf16x8*)&sB[(wc * 32 + u * 16 + l15) * LDT + ks + q8];
#pragma unroll
      for (int t = 0; t < 2; ++t)
#pragma unroll
        for (int u = 0; u < 2; ++u) acc[t][u] = MFMA(fa[t], fb[u], acc[t][u]);
    }
  }
#undef K4_LOAD

  // ---- epilogue: divide, bounce full 64x64 tile through LDS, store bf16x8 ----
  bf16* sBounce = sA;
  __syncthreads();
#pragma unroll
  for (int t = 0; t < 2; ++t)
#pragma unroll
    for (int r = 0; r < 4; ++r) {
      int lr = wr * 32 + t * 16 + q4 + r;
      int row = i0 + lr;
      float inv = 1.f / sums[(((b << 10) + row) << 4) + h];
#pragma unroll
      for (int u = 0; u < 2; ++u)
        sBounce[lr * LDT + wc * 32 + u * 16 + l15] = (bf16)(acc[t][u][r] * inv);
    }
  __syncthreads();
#pragma unroll
  for (int r2 = 0; r2 < 2; ++r2) {
    int lr = r2 * 32 + (tid >> 3);       // 0..63
    int cc = (tid & 7) * 8;              // bf16x8 units over 64 cols
    bf16x8 vv = *(const bf16x8*)&sBounce[lr * LDT + cc];
    *(bf16x8*)(aout + (size_t)(b * Ssz + i0 + lr) * Dsz + h * DHsz + cc) = vv;
  }
}

// ---------------------------------------------------------------------------
// K5: out = aout_bf @ ow_h^T  1-term, fp32 out, tile 64x64 (round-4 verified).
// ---------------------------------------------------------------------------
__global__ __launch_bounds__(256, 6) void k5_out(const bf16* __restrict__ A,
                                                 const bf16* __restrict__ B,
                                                 float* __restrict__ C) {
  __shared__ __align__(16) bf16 sA[64 * LDT], sB[64 * LDT];
  const int tid = threadIdx.x;
  const int lane = tid & 63, wv = tid >> 6;
  const int wr = wv >> 1, wc = wv & 1;
  const int l15 = lane & 15, q8 = (lane >> 4) << 3, q4 = (lane >> 4) << 2;
  const int m0 = blockIdx.y * 64, n0 = blockIdx.x * 64;
  const int r0 = tid >> 3, c8 = (tid & 7) << 3;
  f32x4 acc[2][2];
#pragma unroll
  for (int t = 0; t < 2; ++t)
#pragma unroll
    for (int u = 0; u < 2; ++u)
#pragma unroll
      for (int r = 0; r < 4; ++r) acc[t][u][r] = 0.f;
  bf16x8 rA[2], rB[2];
#define K5_LOAD(kt)                                                       \
  {                                                                       \
    _Pragma("unroll") for (int c = 0; c < 2; ++c) {                       \
      int row = c * 32 + r0;                                              \
      rA[c] = *(const bf16x8*)(A + (size_t)(m0 + row) * Dsz + (kt) + c8);   \
      rB[c] = *(const bf16x8*)(B + (size_t)(n0 + row) * Dsz + (kt) + c8);   \
    }                                                                     \
  }
  K5_LOAD(0)
  for (int kt = 0; kt < Dsz; kt += 64) {
    __syncthreads();
#pragma unroll
    for (int c = 0; c < 2; ++c) {
      int row = c * 32 + r0;
      *(bf16x8*)&sA[row * LDT + c8] = rA[c];
      *(bf16x8*)&sB[row * LDT + c8] = rB[c];
    }
    __syncthreads();
    if (kt + 64 < Dsz) K5_LOAD(kt + 64)
#pragma unroll
    for (int ks = 0; ks < 64; ks += 32) {
      bf16x8 fa[2], fb[2];
#pragma unroll
      for (int t = 0; t < 2; ++t) fa[t] = *(const bf16x8*)&sA[(wr * 32 + t * 16 + l15) * LDT + ks + q8];
#pragma unroll
      for (int u = 0; u < 2; ++u) fb[u] = *(const bf16x8*)&sB[(wc * 32 + u * 16 + l15) * LDT + ks + q8];
#pragma unroll
      for (int t = 0; t < 2; ++t)
#pragma unroll
        for (int u = 0; u < 2; ++u) acc[t][u] = MFMA(fa[t], fb[u], acc[t][u]);
    }
  }
#pragma unroll
  for (int t = 0; t < 2; ++t)
#pragma unroll
    for (int u = 0; u < 2; ++u) {
      int col = n0 + wc * 32 + u * 16 + l15;
#pragma unroll
      for (int r = 0; r < 4; ++r) {
        int row = m0 + wr * 32 + t * 16 + q4 + r;
        C[(size_t)row * Dsz + col] = acc[t][u][r];
      }
    }
#undef K5_LOAD
}

// ---------------------------------------------------------------------------
extern "C" void kernel_launch(void* const* d_in, const int* in_sizes, int n_in,
                              void* d_out, int out_size, void* d_ws, size_t ws_size,
                              hipStream_t stream) {
  const float* x      = (const float*)d_in[0];
  const float* qkv_w  = (const float*)d_in[1];
  const float* out_w  = (const float*)d_in[2];
  const float* bias_p = (const float*)d_in[3];
  const float* bias_a = (const float*)d_in[4];
  const float* w1     = (const float*)d_in[5];
  const float* b1     = (const float*)d_in[6];
  const float* w2     = (const float*)d_in[7];
  const float* b2     = (const float*)d_in[8];
  float* out = (float*)d_out;

  // ws layout (bytes). scores (64 MB) ALIASES x_h/w_h (dead after k1).
  char* ws = (char*)d_ws;
  const size_t MB = 1ull << 20;
  bf16* ow_h   = (bf16*)(ws + 0 * MB);            // 2 MB
  bf16* qkv_bf = (bf16*)(ws + 2 * MB);            // 12 MB
  bf16* v_t    = (bf16*)(ws + 14 * MB);           // 4 MB
  bf16* aout   = (bf16*)(ws + 18 * MB);           // 4 MB
  float* sums  = (float*)(ws + 22 * MB + 65536);  // 128 KB [b][i][h]
  bf16* wf     = (bf16*)(ws + 22 * MB + 589824);  // 2 KB
  float2* tk   = (float2*)(ws + 22 * MB + 655360);// 256 KB [o][n]
  bf16* x_h    = (bf16*)(ws + 23 * MB);           // 4 MB   (dead after k1)
  bf16* w_h    = (bf16*)(ws + 27 * MB);           // 6 MB   (dead after k1)
  bf16* sc_bf  = (bf16*)(ws + 23 * MB);           // 64 MB, ends at 87 MB

  cast_all<<<6144, 256, 0, stream>>>(x, qkv_w, out_w, x_h, w_h, ow_h);
  tk_wfrag<<<129, 256, 0, stream>>>(bias_p, bias_a, w1, b1, w2, tk, wf);

  k1_qkv<<<dim3(QKV3 / 96, (Bsz * Ssz) / 128), 256, 0, stream>>>(x_h, w_h, qkv_bf);
  pack_vt<<<dim3(Ssz / 64, Bsz * Hn), 256, 0, stream>>>(qkv_bf, v_t);

  k2_qk<<<dim3(Ssz / 128, Ssz / 128, Bsz * Hn), 256, 0, stream>>>(qkv_bf, sc_bf);
  dape_softmax<<<dim3(Ssz, Bsz), 1024, 0, stream>>>(sc_bf, tk, wf, b2, sums);
  k4_av<<<dim3(Ssz / 64, Hn, Bsz), 256, 0, stream>>>(sc_bf, v_t, sums, aout);

  k5_out<<<dim3(Dsz / 64, (Bsz * Ssz) / 64), 256, 0, stream>>>(aout, ow_h, out);
}